// Round 6
// baseline (353.584 us; speedup 1.0000x reference)
//
#include <hip/hip_runtime.h>
#include <hip/hip_bf16.h>
#include <math.h>

typedef __bf16 bf16_t;
typedef bf16_t bf16x4 __attribute__((ext_vector_type(4)));
typedef bf16_t bf16x8 __attribute__((ext_vector_type(8)));
typedef float f32x4 __attribute__((ext_vector_type(4)));

#define T_TOK 8192
#define HDIM  1024
#define IDIM  512
#define NEXP  8
#define NTOT  12
#define MAXROWS (2 * T_TOK + NEXP * 128)   // 17408
#define MAX_MTILES (MAXROWS / 128)         // 136

// ---------------- async global->LDS, 16B per lane (dest: wave-uniform base + lane*16) ----
__device__ __forceinline__ void gll16(const bf16_t* g, bf16_t* l) {
  __builtin_amdgcn_global_load_lds((__attribute__((address_space(1))) void*)g,
                                   (__attribute__((address_space(3))) void*)l,
                                   16, 0, 0);
}

// ---------------- fused weight cast: w13 + w2 -> bf16 ----------------
#define N1G (NEXP * 2 * IDIM * HDIM / 8)   // 1048576 groups of 8
#define N2G (NEXP * HDIM * IDIM / 8)       // 524288
__global__ void cast_w_kernel(const float* __restrict__ w13, const float* __restrict__ w2,
                              bf16_t* __restrict__ w13b, bf16_t* __restrict__ w2b) {
  size_t gid = (size_t)blockIdx.x * blockDim.x + threadIdx.x;
  const float* src;
  bf16_t* dst;
  if (gid < N1G) { src = w13 + gid * 8; dst = w13b + gid * 8; }
  else { size_t g2 = gid - N1G; if (g2 >= N2G) return; src = w2 + g2 * 8; dst = w2b + g2 * 8; }
  float4 a = *(const float4*)src;
  float4 b = *(const float4*)(src + 4);
  bf16x8 o;
  o[0] = (bf16_t)a.x; o[1] = (bf16_t)a.y; o[2] = (bf16_t)a.z; o[3] = (bf16_t)a.w;
  o[4] = (bf16_t)b.x; o[5] = (bf16_t)b.y; o[6] = (bf16_t)b.z; o[7] = (bf16_t)b.w;
  *(bf16x8*)dst = o;
}

// ---------------- zero counts ----------------
__global__ void zero_counts_kernel(int* __restrict__ counts) {
  if (threadIdx.x < NEXP) counts[threadIdx.x] = 0;
}

// ---------------- router + count: 4 tokens/block (1 wave each), LDS histogram --------
__global__ void router_kernel(const float* __restrict__ x, const float* __restrict__ rw,
                              const float* __restrict__ bias,
                              int* __restrict__ tk_e, float* __restrict__ tk_w,
                              float* __restrict__ zscale, int* __restrict__ counts) {
  __shared__ int lc[NEXP];
  int tid = threadIdx.x;
  if (tid < NEXP) lc[tid] = 0;
  __syncthreads();
  int t = blockIdx.x * 4 + (tid >> 6);
  int l = tid & 63;
  const float4* xr = (const float4*)(x + (size_t)t * HDIM);
  float4 xv[4];
#pragma unroll
  for (int i = 0; i < 4; i++) xv[i] = xr[l + 64 * i];
  float part[NTOT];
#pragma unroll
  for (int e = 0; e < NTOT; e++) {
    const float4* wr = (const float4*)(rw + (size_t)e * HDIM);
    float s = 0.f;
#pragma unroll
    for (int i = 0; i < 4; i++) {
      float4 w = wr[l + 64 * i];
      s += xv[i].x * w.x + xv[i].y * w.y + xv[i].z * w.z + xv[i].w * w.w;
    }
    part[e] = s;
  }
#pragma unroll
  for (int off = 32; off > 0; off >>= 1)
#pragma unroll
    for (int e = 0; e < NTOT; e++) part[e] += __shfl_down(part[e], off);

  if (l == 0) {
    float mx = part[0];
#pragma unroll
    for (int e = 1; e < NTOT; e++) mx = fmaxf(mx, part[e]);
    float p[NTOT], den = 0.f;
#pragma unroll
    for (int e = 0; e < NTOT; e++) { p[e] = expf(part[e] - mx); den += p[e]; }
    float inv = 1.f / den;
#pragma unroll
    for (int e = 0; e < NTOT; e++) p[e] *= inv;
    float s0 = -1e30f, s1 = -1e30f; int i0 = 0, i1 = 0;
#pragma unroll
    for (int e = 0; e < NTOT; e++) {
      float v = p[e] + bias[e];
      if (v > s0) { s1 = s0; i1 = i0; s0 = v; i0 = e; }
      else if (v > s1) { s1 = v; i1 = e; }
    }
    float zs = 0.f;
    int idx[2] = { i0, i1 };
#pragma unroll
    for (int k = 0; k < 2; k++) {
      int e = idx[k];
      float w = p[e];
      if (e >= NEXP) { zs += w; tk_e[2 * t + k] = -1; tk_w[2 * t + k] = 0.f; }
      else { tk_e[2 * t + k] = e; tk_w[2 * t + k] = w; atomicAdd(&lc[e], 1); }
    }
    zscale[t] = zs;
  }
  __syncthreads();
  if (tid < NEXP && lc[tid]) atomicAdd(&counts[tid], lc[tid]);
}

// ---------------- scan: offsets + tile list + zero pad sel entries ----------------
__global__ void scan_kernel(const int* __restrict__ counts, int* __restrict__ cursor,
                            int* __restrict__ tile_e, int* __restrict__ tile_p0,
                            int* __restrict__ n_mtiles,
                            int* __restrict__ sel_tok, float* __restrict__ sel_w) {
  __shared__ int s_off[NEXP], s_cnt[NEXP];
  if (threadIdx.x == 0) {
    int run = 0, nt = 0;
    for (int e = 0; e < NEXP; e++) {
      s_off[e] = run; s_cnt[e] = counts[e];
      cursor[e] = run;
      int ntile = (s_cnt[e] + 127) / 128;
      for (int i = 0; i < ntile; i++) { tile_e[nt] = e; tile_p0[nt] = run + i * 128; nt++; }
      run += ntile * 128;
    }
    *n_mtiles = nt;
  }
  __syncthreads();
  for (int i = threadIdx.x; i < NEXP * 128; i += blockDim.x) {
    int e = i >> 7, idx = i & 127;
    int c = s_cnt[e];
    int padded = ((c + 127) / 128) * 128;
    int pos = c + idx;
    if (pos < padded) { sel_tok[s_off[e] + pos] = 0; sel_w[s_off[e] + pos] = 0.f; }
  }
}

// ---------------- assign + gather + out-init (one x read) ----------------
__global__ __launch_bounds__(256) void assign_gather_kernel(
    const float* __restrict__ x, const int* __restrict__ tk_e, const float* __restrict__ tk_w,
    const float* __restrict__ zscale, int* __restrict__ cursor,
    int* __restrict__ sel_tok, float* __restrict__ sel_w,
    bf16_t* __restrict__ xg, float* __restrict__ out) {
  __shared__ int lc[NEXP], lbase[NEXP];
  __shared__ int s_p0[256], s_p1[256];
  __shared__ float s_zs[256];
  int tid = threadIdx.x;
  int t = blockIdx.x * 256 + tid;
  if (tid < NEXP) lc[tid] = 0;
  __syncthreads();
  int e0 = tk_e[2 * t], e1 = tk_e[2 * t + 1];
  int r0 = (e0 >= 0) ? atomicAdd(&lc[e0], 1) : -1;
  int r1 = (e1 >= 0) ? atomicAdd(&lc[e1], 1) : -1;
  __syncthreads();
  if (tid < NEXP) lbase[tid] = lc[tid] ? atomicAdd(&cursor[tid], lc[tid]) : 0;
  __syncthreads();
  int p0 = -1, p1 = -1;
  if (e0 >= 0) { p0 = lbase[e0] + r0; sel_tok[p0] = t; sel_w[p0] = 2.5f * tk_w[2 * t]; }
  if (e1 >= 0) { p1 = lbase[e1] + r1; sel_tok[p1] = t; sel_w[p1] = 2.5f * tk_w[2 * t + 1]; }
  s_p0[tid] = p0; s_p1[tid] = p1; s_zs[tid] = zscale[t];
  __syncthreads();

  size_t tbase = (size_t)blockIdx.x * 256;
  int j = tid * 4;  // 256 threads x 4 floats = 1024 cols
  for (int i = 0; i < 256; i++) {
    float4 v = *(const float4*)&x[(tbase + i) * HDIM + j];
    float zs = s_zs[i];
    *(float4*)&out[(tbase + i) * HDIM + j] = make_float4(zs * v.x, zs * v.y, zs * v.z, zs * v.w);
    bf16x4 b;
    b[0] = (bf16_t)v.x; b[1] = (bf16_t)v.y; b[2] = (bf16_t)v.z; b[3] = (bf16_t)v.w;
    int q0 = s_p0[i], q1 = s_p1[i];
    if (q0 >= 0) *(bf16x4*)&xg[(size_t)q0 * HDIM + j] = b;
    if (q1 >= 0) *(bf16x4*)&xg[(size_t)q1 * HDIM + j] = b;
  }
}

// ---------------- fused GEMM1+SiLU: 128x128 (64 gate + 64 up interleaved) ----------------
// LDS k-major: elem(row, k=kc*8+j) at plane kc (1024 elems) + row*8 + j  -> ds_read_b128
// by lanes c16=0..15 is 2-way bank aliasing = free.
// B-tile row r -> w13 col: g0 + (r>>6)*32 + (((r>>4)&1)*16) + (r&15), +IDIM if (r>>5)&1
__global__ __launch_bounds__(256) void gemm1_kernel(
    const bf16_t* __restrict__ xg, const bf16_t* __restrict__ w13b,
    const int* __restrict__ tile_e, const int* __restrict__ tile_p0,
    const int* __restrict__ n_mtiles, bf16_t* __restrict__ actb) {
  const int yb = blockIdx.x & 7;          // XCD-pinned weight slice
  const int ti = blockIdx.x >> 3;
  if (ti >= *n_mtiles) return;
  const int e = tile_e[ti];
  const int p0 = tile_p0[ti];
  const int g0 = yb * 64;

  __shared__ alignas(16) bf16_t As[4096];  // 4 planes x 128 rows x 8
  __shared__ alignas(16) bf16_t Bs[4096];

  const int tid = threadIdx.x;
  const int w = tid >> 6, l = tid & 63;
  const int wr = w >> 1, wc = w & 1;
  const int quad = l >> 4, c16 = l & 15;

  // staging: wave w = k-chunk w; lane l = row (two 64-row halves)
  const bf16_t* Asrc0 = xg + (size_t)(p0 + l) * HDIM + w * 8;
  const bf16_t* Asrc1 = Asrc0 + (size_t)64 * HDIM;
  int rB0 = l, rB1 = l + 64;
  int col0 = g0 + (rB0 >> 6) * 32 + (((rB0 >> 4) & 1) * 16) + (rB0 & 15) + (((rB0 >> 5) & 1) ? IDIM : 0);
  int col1 = g0 + (rB1 >> 6) * 32 + (((rB1 >> 4) & 1) * 16) + (rB1 & 15) + (((rB1 >> 5) & 1) ? IDIM : 0);
  const bf16_t* w13e = w13b + (size_t)e * (2 * IDIM) * HDIM;
  const bf16_t* Bsrc0 = w13e + (size_t)col0 * HDIM + w * 8;
  const bf16_t* Bsrc1 = w13e + (size_t)col1 * HDIM + w * 8;
  bf16_t* Adst0 = &As[w * 1024];
  bf16_t* Adst1 = &As[w * 1024 + 512];
  bf16_t* Bdst0 = &Bs[w * 1024];
  bf16_t* Bdst1 = &Bs[w * 1024 + 512];

  int aoff[4], boff[4];
#pragma unroll
  for (int mt = 0; mt < 4; mt++) aoff[mt] = quad * 1024 + (wr * 64 + mt * 16 + c16) * 8;
#pragma unroll
  for (int nt = 0; nt < 4; nt++) boff[nt] = quad * 1024 + (wc * 64 + nt * 16 + c16) * 8;

  f32x4 acc[4][4];
#pragma unroll
  for (int i = 0; i < 4; i++)
#pragma unroll
    for (int j = 0; j < 4; j++) acc[i][j] = (f32x4){0.f, 0.f, 0.f, 0.f};

  for (int k0 = 0; k0 < HDIM; k0 += 32) {
    gll16(Asrc0 + k0, Adst0);
    gll16(Asrc1 + k0, Adst1);
    gll16(Bsrc0 + k0, Bdst0);
    gll16(Bsrc1 + k0, Bdst1);
    __syncthreads();
    bf16x8 af[4], bfv[4];
#pragma unroll
    for (int mt = 0; mt < 4; mt++) af[mt] = *(const bf16x8*)&As[aoff[mt]];
#pragma unroll
    for (int nt = 0; nt < 4; nt++) bfv[nt] = *(const bf16x8*)&Bs[boff[nt]];
#pragma unroll
    for (int mt = 0; mt < 4; mt++)
#pragma unroll
      for (int nt = 0; nt < 4; nt++)
        acc[mt][nt] = __builtin_amdgcn_mfma_f32_16x16x32_bf16(af[mt], bfv[nt], acc[mt][nt], 0, 0, 0);
    __syncthreads();
  }

  // epilogue: act = silu(gate)*up; gate=acc[mt][nt], up=acc[mt][nt+2], same lane
#pragma unroll
  for (int mt = 0; mt < 4; mt++) {
    int rowb = p0 + wr * 64 + mt * 16 + quad * 4;
#pragma unroll
    for (int nt = 0; nt < 2; nt++) {
      int col = g0 + wc * 32 + nt * 16 + c16;
#pragma unroll
      for (int r = 0; r < 4; r++) {
        float g = acc[mt][nt][r];
        float u = acc[mt][nt + 2][r];
        actb[(size_t)(rowb + r) * IDIM + col] = (bf16_t)(g / (1.f + expf(-g)) * u);
      }
    }
  }
}

// ---------------- GEMM2: 128x128, atomic accumulate into out ----------------
__global__ __launch_bounds__(256) void gemm2_kernel(
    const bf16_t* __restrict__ actb, const bf16_t* __restrict__ w2b,
    const float* __restrict__ sel_w, const int* __restrict__ sel_tok,
    const int* __restrict__ tile_e, const int* __restrict__ tile_p0,
    const int* __restrict__ n_mtiles, float* __restrict__ out) {
  const int yb = blockIdx.x & 7;
  const int ti = blockIdx.x >> 3;
  if (ti >= *n_mtiles) return;
  const int e = tile_e[ti];
  const int p0 = tile_p0[ti];
  const int n0 = yb * 128;

  __shared__ alignas(16) bf16_t As[4096];
  __shared__ alignas(16) bf16_t Bs[4096];

  const int tid = threadIdx.x;
  const int w = tid >> 6, l = tid & 63;
  const int wr = w >> 1, wc = w & 1;
  const int quad = l >> 4, c16 = l & 15;

  const bf16_t* Asrc0 = actb + (size_t)(p0 + l) * IDIM + w * 8;
  const bf16_t* Asrc1 = Asrc0 + (size_t)64 * IDIM;
  const bf16_t* w2e = w2b + (size_t)e * HDIM * IDIM;
  const bf16_t* Bsrc0 = w2e + (size_t)(n0 + l) * IDIM + w * 8;
  const bf16_t* Bsrc1 = Bsrc0 + (size_t)64 * IDIM;
  bf16_t* Adst0 = &As[w * 1024];
  bf16_t* Adst1 = &As[w * 1024 + 512];
  bf16_t* Bdst0 = &Bs[w * 1024];
  bf16_t* Bdst1 = &Bs[w * 1024 + 512];

  int aoff[4], boff[4];
#pragma unroll
  for (int mt = 0; mt < 4; mt++) aoff[mt] = quad * 1024 + (wr * 64 + mt * 16 + c16) * 8;
#pragma unroll
  for (int nt = 0; nt < 4; nt++) boff[nt] = quad * 1024 + (wc * 64 + nt * 16 + c16) * 8;

  f32x4 acc[4][4];
#pragma unroll
  for (int i = 0; i < 4; i++)
#pragma unroll
    for (int j = 0; j < 4; j++) acc[i][j] = (f32x4){0.f, 0.f, 0.f, 0.f};

  for (int k0 = 0; k0 < IDIM; k0 += 32) {
    gll16(Asrc0 + k0, Adst0);
    gll16(Asrc1 + k0, Adst1);
    gll16(Bsrc0 + k0, Bdst0);
    gll16(Bsrc1 + k0, Bdst1);
    __syncthreads();
    bf16x8 af[4], bfv[4];
#pragma unroll
    for (int mt = 0; mt < 4; mt++) af[mt] = *(const bf16x8*)&As[aoff[mt]];
#pragma unroll
    for (int nt = 0; nt < 4; nt++) bfv[nt] = *(const bf16x8*)&Bs[boff[nt]];
#pragma unroll
    for (int mt = 0; mt < 4; mt++)
#pragma unroll
      for (int nt = 0; nt < 4; nt++)
        acc[mt][nt] = __builtin_amdgcn_mfma_f32_16x16x32_bf16(af[mt], bfv[nt], acc[mt][nt], 0, 0, 0);
    __syncthreads();
  }

  // epilogue: out[tok][col] += sel_w * acc  (fp32 atomics; pad rows have sel_w=0)
#pragma unroll
  for (int mt = 0; mt < 4; mt++) {
    int rowb = p0 + wr * 64 + mt * 16 + quad * 4;
#pragma unroll
    for (int r = 0; r < 4; r++) {
      int p = rowb + r;
      float cw = sel_w[p];
      if (cw == 0.f) continue;
      size_t obase = (size_t)sel_tok[p] * HDIM;
#pragma unroll
      for (int nt = 0; nt < 4; nt++) {
        int col = n0 + wc * 64 + nt * 16 + c16;
        atomicAdd(&out[obase + col], cw * acc[mt][nt][r]);
      }
    }
  }
}

extern "C" void kernel_launch(void* const* d_in, const int* in_sizes, int n_in,
                              void* d_out, int out_size, void* d_ws, size_t ws_size,
                              hipStream_t stream) {
  const float* x    = (const float*)d_in[0];
  const float* rw   = (const float*)d_in[1];
  const float* bias = (const float*)d_in[2];
  const float* w13  = (const float*)d_in[3];
  const float* w2   = (const float*)d_in[4];
  float* out = (float*)d_out;

  char* ws = (char*)d_ws;
  bf16_t* w13b = (bf16_t*)ws;  ws += (size_t)NEXP * 2 * IDIM * HDIM * 2;
  bf16_t* w2b  = (bf16_t*)ws;  ws += (size_t)NEXP * HDIM * IDIM * 2;
  bf16_t* xg   = (bf16_t*)ws;  ws += (size_t)MAXROWS * HDIM * 2;
  bf16_t* actb = (bf16_t*)ws;  ws += (size_t)MAXROWS * IDIM * 2;
  int*   tk_e    = (int*)ws;   ws += (size_t)T_TOK * 2 * 4;
  float* tk_w    = (float*)ws; ws += (size_t)T_TOK * 2 * 4;
  float* zscale  = (float*)ws; ws += (size_t)T_TOK * 4;
  int*   sel_tok = (int*)ws;   ws += (size_t)MAXROWS * 4;
  float* sel_w   = (float*)ws; ws += (size_t)MAXROWS * 4;
  int*   counts  = (int*)ws;   ws += NEXP * 4;
  int*   cursor  = (int*)ws;   ws += NEXP * 4;
  int*   tile_e  = (int*)ws;   ws += MAX_MTILES * 4;
  int*   tile_p0 = (int*)ws;   ws += MAX_MTILES * 4;
  int*   n_mtiles = (int*)ws;  ws += 4;

  zero_counts_kernel<<<1, 64, 0, stream>>>(counts);
  cast_w_kernel<<<(N1G + N2G + 255) / 256, 256, 0, stream>>>(w13, w2, w13b, w2b);
  router_kernel<<<T_TOK / 4, 256, 0, stream>>>(x, rw, bias, tk_e, tk_w, zscale, counts);
  scan_kernel<<<1, 256, 0, stream>>>(counts, cursor, tile_e, tile_p0, n_mtiles, sel_tok, sel_w);
  assign_gather_kernel<<<T_TOK / 256, 256, 0, stream>>>(
      x, tk_e, tk_w, zscale, cursor, sel_tok, sel_w, xg, out);

  gemm1_kernel<<<MAX_MTILES * 8, 256, 0, stream>>>(
      xg, w13b, tile_e, tile_p0, n_mtiles, actb);
  gemm2_kernel<<<MAX_MTILES * 8, 256, 0, stream>>>(
      actb, w2b, sel_w, sel_tok, tile_e, tile_p0, n_mtiles, out);
}

// Round 7
// 264.679 us; speedup vs baseline: 1.3359x; 1.3359x over previous
//
#include <hip/hip_runtime.h>
#include <hip/hip_bf16.h>
#include <math.h>

typedef __bf16 bf16_t;
typedef bf16_t bf16x8 __attribute__((ext_vector_type(8)));
typedef float f32x4 __attribute__((ext_vector_type(4)));

#define T_TOK 8192
#define HDIM  1024
#define IDIM  512
#define NEXP  8
#define NTOT  12
#define MAXROWS (2 * T_TOK + NEXP * 128)   // 17408
#define MAX_MTILES (MAXROWS / 128)         // 136

// ---------------- async global->LDS, 16B per lane ----------------
__device__ __forceinline__ void gll16(const bf16_t* g, bf16_t* l) {
  __builtin_amdgcn_global_load_lds((__attribute__((address_space(1))) void*)g,
                                   (__attribute__((address_space(3))) void*)l,
                                   16, 0, 0);
}

__device__ __forceinline__ bf16x8 cvt8(float4 f0, float4 f1) {
  bf16x8 t;
  t[0] = (bf16_t)f0.x; t[1] = (bf16_t)f0.y; t[2] = (bf16_t)f0.z; t[3] = (bf16_t)f0.w;
  t[4] = (bf16_t)f1.x; t[5] = (bf16_t)f1.y; t[6] = (bf16_t)f1.z; t[7] = (bf16_t)f1.w;
  return t;
}

// ---------------- fused weight cast: w13 + w2 -> bf16 ----------------
#define N1G (NEXP * 2 * IDIM * HDIM / 8)   // 1048576
#define N2G (NEXP * HDIM * IDIM / 8)       // 524288
__global__ void cast_w_kernel(const float* __restrict__ w13, const float* __restrict__ w2,
                              bf16_t* __restrict__ w13b, bf16_t* __restrict__ w2b) {
  size_t gid = (size_t)blockIdx.x * blockDim.x + threadIdx.x;
  const float* src;
  bf16_t* dst;
  if (gid < N1G) { src = w13 + gid * 8; dst = w13b + gid * 8; }
  else { size_t g2 = gid - N1G; if (g2 >= N2G) return; src = w2 + g2 * 8; dst = w2b + g2 * 8; }
  float4 a = *(const float4*)src;
  float4 b = *(const float4*)(src + 4);
  *(bf16x8*)dst = cvt8(a, b);
}

// ---------------- zero counts ----------------
__global__ void zero_counts_kernel(int* __restrict__ counts) {
  if (threadIdx.x < NEXP) counts[threadIdx.x] = 0;
}

// ---------------- router + count ----------------
__global__ void router_kernel(const float* __restrict__ x, const float* __restrict__ rw,
                              const float* __restrict__ bias,
                              int* __restrict__ tk_e, float* __restrict__ tk_w,
                              float* __restrict__ zscale, int* __restrict__ counts) {
  __shared__ int lc[NEXP];
  int tid = threadIdx.x;
  if (tid < NEXP) lc[tid] = 0;
  __syncthreads();
  int t = blockIdx.x * 4 + (tid >> 6);
  int l = tid & 63;
  const float4* xr = (const float4*)(x + (size_t)t * HDIM);
  float4 xv[4];
#pragma unroll
  for (int i = 0; i < 4; i++) xv[i] = xr[l + 64 * i];
  float part[NTOT];
#pragma unroll
  for (int e = 0; e < NTOT; e++) {
    const float4* wr = (const float4*)(rw + (size_t)e * HDIM);
    float s = 0.f;
#pragma unroll
    for (int i = 0; i < 4; i++) {
      float4 w = wr[l + 64 * i];
      s += xv[i].x * w.x + xv[i].y * w.y + xv[i].z * w.z + xv[i].w * w.w;
    }
    part[e] = s;
  }
#pragma unroll
  for (int off = 32; off > 0; off >>= 1)
#pragma unroll
    for (int e = 0; e < NTOT; e++) part[e] += __shfl_down(part[e], off);

  if (l == 0) {
    float mx = part[0];
#pragma unroll
    for (int e = 1; e < NTOT; e++) mx = fmaxf(mx, part[e]);
    float p[NTOT], den = 0.f;
#pragma unroll
    for (int e = 0; e < NTOT; e++) { p[e] = expf(part[e] - mx); den += p[e]; }
    float inv = 1.f / den;
#pragma unroll
    for (int e = 0; e < NTOT; e++) p[e] *= inv;
    float s0 = -1e30f, s1 = -1e30f; int i0 = 0, i1 = 0;
#pragma unroll
    for (int e = 0; e < NTOT; e++) {
      float v = p[e] + bias[e];
      if (v > s0) { s1 = s0; i1 = i0; s0 = v; i0 = e; }
      else if (v > s1) { s1 = v; i1 = e; }
    }
    float zs = 0.f;
    int idx[2] = { i0, i1 };
#pragma unroll
    for (int k = 0; k < 2; k++) {
      int e = idx[k];
      float w = p[e];
      if (e >= NEXP) { zs += w; tk_e[2 * t + k] = -1; tk_w[2 * t + k] = 0.f; }
      else { tk_e[2 * t + k] = e; tk_w[2 * t + k] = w; atomicAdd(&lc[e], 1); }
    }
    zscale[t] = zs;
  }
  __syncthreads();
  if (tid < NEXP && lc[tid]) atomicAdd(&counts[tid], lc[tid]);
}

// ---------------- scan: tile list + cursor + zero pad sel entries ----------------
__global__ void scan_kernel(const int* __restrict__ counts, int* __restrict__ cursor,
                            int* __restrict__ tile_e, int* __restrict__ tile_p0,
                            int* __restrict__ n_mtiles,
                            int* __restrict__ sel_tok, float* __restrict__ sel_w) {
  __shared__ int s_off[NEXP], s_cnt[NEXP];
  if (threadIdx.x == 0) {
    int run = 0, nt = 0;
    for (int e = 0; e < NEXP; e++) {
      s_off[e] = run; s_cnt[e] = counts[e];
      cursor[e] = run;
      int ntile = (s_cnt[e] + 127) / 128;
      for (int i = 0; i < ntile; i++) { tile_e[nt] = e; tile_p0[nt] = run + i * 128; nt++; }
      run += ntile * 128;
    }
    *n_mtiles = nt;
  }
  __syncthreads();
  for (int i = threadIdx.x; i < NEXP * 128; i += blockDim.x) {
    int e = i >> 7, idx = i & 127;
    int c = s_cnt[e];
    int padded = ((c + 127) / 128) * 128;
    int pos = c + idx;
    if (pos < padded) { sel_tok[s_off[e] + pos] = 0; sel_w[s_off[e] + pos] = 0.f; }
  }
}

// ---------------- assign: scatter selections, record per-token positions ----------------
__global__ void assign_kernel(const int* __restrict__ tk_e, const float* __restrict__ tk_w,
                              int* __restrict__ cursor, int* __restrict__ sel_tok,
                              float* __restrict__ sel_w, int* __restrict__ pos) {
  __shared__ int lc[NEXP], lbase[NEXP];
  int tid = threadIdx.x;
  if (tid < NEXP) lc[tid] = 0;
  __syncthreads();
  int t = blockIdx.x * blockDim.x + tid;
  int e0 = tk_e[2 * t], e1 = tk_e[2 * t + 1];
  int r0 = (e0 >= 0) ? atomicAdd(&lc[e0], 1) : -1;
  int r1 = (e1 >= 0) ? atomicAdd(&lc[e1], 1) : -1;
  __syncthreads();
  if (tid < NEXP) lbase[tid] = lc[tid] ? atomicAdd(&cursor[tid], lc[tid]) : 0;
  __syncthreads();
  int p0 = -1, p1 = -1;
  if (e0 >= 0) { p0 = lbase[e0] + r0; sel_tok[p0] = t; sel_w[p0] = 2.5f * tk_w[2 * t]; }
  if (e1 >= 0) { p1 = lbase[e1] + r1; sel_tok[p1] = t; sel_w[p1] = 2.5f * tk_w[2 * t + 1]; }
  pos[2 * t] = p0;
  pos[2 * t + 1] = p1;
}

// ---------------- gather + out-init: out = zs*x ; xg[p0]=xg[p1]=bf16(x) ----------------
__global__ void gather_out_kernel(const float* __restrict__ x, const float* __restrict__ zscale,
                                  const int* __restrict__ pos, bf16_t* __restrict__ xg,
                                  float* __restrict__ out) {
  size_t gid = (size_t)blockIdx.x * blockDim.x + threadIdx.x;  // T * H/8
  size_t t = gid >> 7;
  int j = (int)(gid & 127) * 8;
  float zs = zscale[t];
  int p0 = pos[2 * t], p1 = pos[2 * t + 1];
  float4 a = *(const float4*)&x[t * HDIM + j];
  float4 b = *(const float4*)&x[t * HDIM + j + 4];
  *(float4*)&out[t * HDIM + j] = make_float4(zs * a.x, zs * a.y, zs * a.z, zs * a.w);
  *(float4*)&out[t * HDIM + j + 4] = make_float4(zs * b.x, zs * b.y, zs * b.z, zs * b.w);
  bf16x8 o = cvt8(a, b);
  if (p0 >= 0) *(bf16x8*)&xg[(size_t)p0 * HDIM + j] = o;
  if (p1 >= 0) *(bf16x8*)&xg[(size_t)p1 * HDIM + j] = o;
}

// ================= GEMM kernels =================
// LDS layout: row-major 64-B rows (BK=32), chunk XOR-swizzled at the SOURCE side:
// LDS(row, chunk j) = src(row, j ^ ((row>>1)&3)).  gll16 dest stays contiguous;
// fragment ds_read_b128 at offset r*32 + ((quad ^ ((r>>1)&3))*8) is conflict-free
// (round-5 measured 0 conflicts with this read pattern).

// ---------------- fused GEMM1+SiLU: 128 x 64(gate)+64(up) interleaved ----------------
__global__ __launch_bounds__(256) void gemm1_kernel(
    const bf16_t* __restrict__ xg, const bf16_t* __restrict__ w13b,
    const int* __restrict__ tile_e, const int* __restrict__ tile_p0,
    const int* __restrict__ n_mtiles, bf16_t* __restrict__ actb) {
  const int yb = blockIdx.x & 7;          // XCD-pinned weight slice
  const int ti = blockIdx.x >> 3;
  if (ti >= *n_mtiles) return;
  const int e = tile_e[ti];
  const int p0 = tile_p0[ti];
  const int g0 = yb * 64;

  __shared__ alignas(16) bf16_t As[128 * 32];
  __shared__ alignas(16) bf16_t Bs[128 * 32];
  const int tid = threadIdx.x;
  const int w = tid >> 6, l = tid & 63;
  const int wr = w >> 1, wc = w & 1;
  const int quad = l >> 4, c16 = l & 15;

  // staging rows sr, sr+16; source chunk permuted to create swizzled LDS
  const int sr = w * 32 + (l >> 2);
  const int sr1 = sr + 16;
  const int sc0 = ((l & 3) ^ ((sr >> 1) & 3)) * 8;
  const int sc1 = ((l & 3) ^ ((sr1 >> 1) & 3)) * 8;
  const bf16_t* Ag0 = xg + (size_t)(p0 + sr) * HDIM + sc0;
  const bf16_t* Ag1 = xg + (size_t)(p0 + sr1) * HDIM + sc1;
  // B-tile row r -> w13 col (gate/up interleaved per 16-col groups)
  int col0 = g0 + (sr >> 6) * 32 + (((sr >> 4) & 1) * 16) + (sr & 15) + (((sr >> 5) & 1) ? IDIM : 0);
  int col1 = g0 + (sr1 >> 6) * 32 + (((sr1 >> 4) & 1) * 16) + (sr1 & 15) + (((sr1 >> 5) & 1) ? IDIM : 0);
  const bf16_t* w13e = w13b + (size_t)e * (2 * IDIM) * HDIM;
  const bf16_t* Bg0 = w13e + (size_t)col0 * HDIM + sc0;
  const bf16_t* Bg1 = w13e + (size_t)col1 * HDIM + sc1;
  bf16_t* Al0 = &As[(w * 32) * 32];
  bf16_t* Bl0 = &Bs[(w * 32) * 32];

  int aoff[4], boff[4];
#pragma unroll
  for (int mt = 0; mt < 4; mt++) {
    int r = wr * 64 + mt * 16 + c16;
    aoff[mt] = r * 32 + ((quad ^ ((r >> 1) & 3)) * 8);
  }
#pragma unroll
  for (int nt = 0; nt < 4; nt++) {
    int r = wc * 64 + nt * 16 + c16;
    boff[nt] = r * 32 + ((quad ^ ((r >> 1) & 3)) * 8);
  }

  f32x4 acc[4][4];
#pragma unroll
  for (int i = 0; i < 4; i++)
#pragma unroll
    for (int j = 0; j < 4; j++) acc[i][j] = (f32x4){0.f, 0.f, 0.f, 0.f};

  for (int k0 = 0; k0 < HDIM; k0 += 32) {
    gll16(Ag0 + k0, Al0);
    gll16(Ag1 + k0, Al0 + 16 * 32);
    gll16(Bg0 + k0, Bl0);
    gll16(Bg1 + k0, Bl0 + 16 * 32);
    __syncthreads();
    bf16x8 af[4], bfv[4];
#pragma unroll
    for (int mt = 0; mt < 4; mt++) af[mt] = *(const bf16x8*)&As[aoff[mt]];
#pragma unroll
    for (int nt = 0; nt < 4; nt++) bfv[nt] = *(const bf16x8*)&Bs[boff[nt]];
#pragma unroll
    for (int mt = 0; mt < 4; mt++)
#pragma unroll
      for (int nt = 0; nt < 4; nt++)
        acc[mt][nt] = __builtin_amdgcn_mfma_f32_16x16x32_bf16(af[mt], bfv[nt], acc[mt][nt], 0, 0, 0);
    __syncthreads();
  }

  // epilogue: act = silu(gate)*up; gate=acc[mt][nt], up=acc[mt][nt+2] (same lane)
#pragma unroll
  for (int mt = 0; mt < 4; mt++) {
    int rowb = p0 + wr * 64 + mt * 16 + quad * 4;
#pragma unroll
    for (int nt = 0; nt < 2; nt++) {
      int col = g0 + wc * 32 + nt * 16 + c16;
#pragma unroll
      for (int r = 0; r < 4; r++) {
        float g = acc[mt][nt][r];
        float u = acc[mt][nt + 2][r];
        actb[(size_t)(rowb + r) * IDIM + col] = (bf16_t)(g / (1.f + expf(-g)) * u);
      }
    }
  }
}

// ---------------- GEMM2: 128x128, atomic accumulate into out ----------------
__global__ __launch_bounds__(256) void gemm2_kernel(
    const bf16_t* __restrict__ actb, const bf16_t* __restrict__ w2b,
    const float* __restrict__ sel_w, const int* __restrict__ sel_tok,
    const int* __restrict__ tile_e, const int* __restrict__ tile_p0,
    const int* __restrict__ n_mtiles, float* __restrict__ out) {
  const int yb = blockIdx.x & 7;
  const int ti = blockIdx.x >> 3;
  if (ti >= *n_mtiles) return;
  const int e = tile_e[ti];
  const int p0 = tile_p0[ti];
  const int n0 = yb * 128;

  __shared__ alignas(16) bf16_t As[128 * 32];
  __shared__ alignas(16) bf16_t Bs[128 * 32];
  const int tid = threadIdx.x;
  const int w = tid >> 6, l = tid & 63;
  const int wr = w >> 1, wc = w & 1;
  const int quad = l >> 4, c16 = l & 15;

  const int sr = w * 32 + (l >> 2);
  const int sr1 = sr + 16;
  const int sc0 = ((l & 3) ^ ((sr >> 1) & 3)) * 8;
  const int sc1 = ((l & 3) ^ ((sr1 >> 1) & 3)) * 8;
  const bf16_t* Ag0 = actb + (size_t)(p0 + sr) * IDIM + sc0;
  const bf16_t* Ag1 = actb + (size_t)(p0 + sr1) * IDIM + sc1;
  const bf16_t* w2e = w2b + (size_t)e * HDIM * IDIM;
  const bf16_t* Bg0 = w2e + (size_t)(n0 + sr) * IDIM + sc0;
  const bf16_t* Bg1 = w2e + (size_t)(n0 + sr1) * IDIM + sc1;
  bf16_t* Al0 = &As[(w * 32) * 32];
  bf16_t* Bl0 = &Bs[(w * 32) * 32];

  int aoff[4], boff[4];
#pragma unroll
  for (int mt = 0; mt < 4; mt++) {
    int r = wr * 64 + mt * 16 + c16;
    aoff[mt] = r * 32 + ((quad ^ ((r >> 1) & 3)) * 8);
  }
#pragma unroll
  for (int nt = 0; nt < 4; nt++) {
    int r = wc * 64 + nt * 16 + c16;
    boff[nt] = r * 32 + ((quad ^ ((r >> 1) & 3)) * 8);
  }

  f32x4 acc[4][4];
#pragma unroll
  for (int i = 0; i < 4; i++)
#pragma unroll
    for (int j = 0; j < 4; j++) acc[i][j] = (f32x4){0.f, 0.f, 0.f, 0.f};

  for (int k0 = 0; k0 < IDIM; k0 += 32) {
    gll16(Ag0 + k0, Al0);
    gll16(Ag1 + k0, Al0 + 16 * 32);
    gll16(Bg0 + k0, Bl0);
    gll16(Bg1 + k0, Bl0 + 16 * 32);
    __syncthreads();
    bf16x8 af[4], bfv[4];
#pragma unroll
    for (int mt = 0; mt < 4; mt++) af[mt] = *(const bf16x8*)&As[aoff[mt]];
#pragma unroll
    for (int nt = 0; nt < 4; nt++) bfv[nt] = *(const bf16x8*)&Bs[boff[nt]];
#pragma unroll
    for (int mt = 0; mt < 4; mt++)
#pragma unroll
      for (int nt = 0; nt < 4; nt++)
        acc[mt][nt] = __builtin_amdgcn_mfma_f32_16x16x32_bf16(af[mt], bfv[nt], acc[mt][nt], 0, 0, 0);
    __syncthreads();
  }

  // epilogue: out[tok][col] += sel_w * acc  (pad rows: sel_w==0 -> skipped)
#pragma unroll
  for (int mt = 0; mt < 4; mt++) {
    int rowb = p0 + wr * 64 + mt * 16 + quad * 4;
#pragma unroll
    for (int r = 0; r < 4; r++) {
      int p = rowb + r;
      float cw = sel_w[p];
      if (cw == 0.f) continue;
      size_t obase = (size_t)sel_tok[p] * HDIM;
#pragma unroll
      for (int nt = 0; nt < 4; nt++) {
        int col = n0 + wc * 64 + nt * 16 + c16;
        atomicAdd(&out[obase + col], cw * acc[mt][nt][r]);
      }
    }
  }
}

extern "C" void kernel_launch(void* const* d_in, const int* in_sizes, int n_in,
                              void* d_out, int out_size, void* d_ws, size_t ws_size,
                              hipStream_t stream) {
  const float* x    = (const float*)d_in[0];
  const float* rw   = (const float*)d_in[1];
  const float* bias = (const float*)d_in[2];
  const float* w13  = (const float*)d_in[3];
  const float* w2   = (const float*)d_in[4];
  float* out = (float*)d_out;

  char* ws = (char*)d_ws;
  bf16_t* w13b = (bf16_t*)ws;  ws += (size_t)NEXP * 2 * IDIM * HDIM * 2;
  bf16_t* w2b  = (bf16_t*)ws;  ws += (size_t)NEXP * HDIM * IDIM * 2;
  bf16_t* xg   = (bf16_t*)ws;  ws += (size_t)MAXROWS * HDIM * 2;
  bf16_t* actb = (bf16_t*)ws;  ws += (size_t)MAXROWS * IDIM * 2;
  int*   tk_e    = (int*)ws;   ws += (size_t)T_TOK * 2 * 4;
  float* tk_w    = (float*)ws; ws += (size_t)T_TOK * 2 * 4;
  float* zscale  = (float*)ws; ws += (size_t)T_TOK * 4;
  int*   pos     = (int*)ws;   ws += (size_t)T_TOK * 2 * 4;
  int*   sel_tok = (int*)ws;   ws += (size_t)MAXROWS * 4;
  float* sel_w   = (float*)ws; ws += (size_t)MAXROWS * 4;
  int*   counts  = (int*)ws;   ws += NEXP * 4;
  int*   cursor  = (int*)ws;   ws += NEXP * 4;
  int*   tile_e  = (int*)ws;   ws += MAX_MTILES * 4;
  int*   tile_p0 = (int*)ws;   ws += MAX_MTILES * 4;
  int*   n_mtiles = (int*)ws;  ws += 4;

  zero_counts_kernel<<<1, 64, 0, stream>>>(counts);
  cast_w_kernel<<<(N1G + N2G + 255) / 256, 256, 0, stream>>>(w13, w2, w13b, w2b);
  router_kernel<<<T_TOK / 4, 256, 0, stream>>>(x, rw, bias, tk_e, tk_w, zscale, counts);
  scan_kernel<<<1, 256, 0, stream>>>(counts, cursor, tile_e, tile_p0, n_mtiles, sel_tok, sel_w);
  assign_kernel<<<T_TOK / 256, 256, 0, stream>>>(tk_e, tk_w, cursor, sel_tok, sel_w, pos);
  gather_out_kernel<<<(size_t)T_TOK * (HDIM / 8) / 256, 256, 0, stream>>>(
      x, zscale, pos, xg, out);

  gemm1_kernel<<<MAX_MTILES * 8, 256, 0, stream>>>(
      xg, w13b, tile_e, tile_p0, n_mtiles, actb);
  gemm2_kernel<<<MAX_MTILES * 8, 256, 0, stream>>>(
      actb, w2b, sel_w, sel_tok, tile_e, tile_p0, n_mtiles, out);
}

// Round 8
// 259.232 us; speedup vs baseline: 1.3640x; 1.0210x over previous
//
#include <hip/hip_runtime.h>
#include <hip/hip_bf16.h>
#include <math.h>

typedef __bf16 bf16_t;
typedef bf16_t bf16x8 __attribute__((ext_vector_type(8)));
typedef float f32x4 __attribute__((ext_vector_type(4)));

#define T_TOK 8192
#define HDIM  1024
#define IDIM  512
#define NEXP  8
#define NTOT  12
#define MAXROWS (2 * T_TOK + NEXP * 128)   // 17408
#define MAX_MTILES (MAXROWS / 128)         // 136
#define BK 64

// ---------------- async global->LDS, 16B per lane ----------------
__device__ __forceinline__ void gll16(const bf16_t* g, bf16_t* l) {
  __builtin_amdgcn_global_load_lds((__attribute__((address_space(1))) void*)g,
                                   (__attribute__((address_space(3))) void*)l,
                                   16, 0, 0);
}

__device__ __forceinline__ bf16x8 cvt8(float4 f0, float4 f1) {
  bf16x8 t;
  t[0] = (bf16_t)f0.x; t[1] = (bf16_t)f0.y; t[2] = (bf16_t)f0.z; t[3] = (bf16_t)f0.w;
  t[4] = (bf16_t)f1.x; t[5] = (bf16_t)f1.y; t[6] = (bf16_t)f1.z; t[7] = (bf16_t)f1.w;
  return t;
}

// ---------------- fused weight cast ----------------
#define N1G (NEXP * 2 * IDIM * HDIM / 8)
#define N2G (NEXP * HDIM * IDIM / 8)
__global__ void cast_w_kernel(const float* __restrict__ w13, const float* __restrict__ w2,
                              bf16_t* __restrict__ w13b, bf16_t* __restrict__ w2b) {
  size_t gid = (size_t)blockIdx.x * blockDim.x + threadIdx.x;
  const float* src;
  bf16_t* dst;
  if (gid < N1G) { src = w13 + gid * 8; dst = w13b + gid * 8; }
  else { size_t g2 = gid - N1G; if (g2 >= N2G) return; src = w2 + g2 * 8; dst = w2b + g2 * 8; }
  float4 a = *(const float4*)src;
  float4 b = *(const float4*)(src + 4);
  *(bf16x8*)dst = cvt8(a, b);
}

// ---------------- zero counts ----------------
__global__ void zero_counts_kernel(int* __restrict__ counts) {
  if (threadIdx.x < NEXP) counts[threadIdx.x] = 0;
}

// ---------------- router + count ----------------
__global__ void router_kernel(const float* __restrict__ x, const float* __restrict__ rw,
                              const float* __restrict__ bias,
                              int* __restrict__ tk_e, float* __restrict__ tk_w,
                              float* __restrict__ zscale, int* __restrict__ counts) {
  __shared__ int lc[NEXP];
  int tid = threadIdx.x;
  if (tid < NEXP) lc[tid] = 0;
  __syncthreads();
  int t = blockIdx.x * 4 + (tid >> 6);
  int l = tid & 63;
  const float4* xr = (const float4*)(x + (size_t)t * HDIM);
  float4 xv[4];
#pragma unroll
  for (int i = 0; i < 4; i++) xv[i] = xr[l + 64 * i];
  float part[NTOT];
#pragma unroll
  for (int e = 0; e < NTOT; e++) {
    const float4* wr = (const float4*)(rw + (size_t)e * HDIM);
    float s = 0.f;
#pragma unroll
    for (int i = 0; i < 4; i++) {
      float4 w = wr[l + 64 * i];
      s += xv[i].x * w.x + xv[i].y * w.y + xv[i].z * w.z + xv[i].w * w.w;
    }
    part[e] = s;
  }
#pragma unroll
  for (int off = 32; off > 0; off >>= 1)
#pragma unroll
    for (int e = 0; e < NTOT; e++) part[e] += __shfl_down(part[e], off);

  if (l == 0) {
    float mx = part[0];
#pragma unroll
    for (int e = 1; e < NTOT; e++) mx = fmaxf(mx, part[e]);
    float p[NTOT], den = 0.f;
#pragma unroll
    for (int e = 0; e < NTOT; e++) { p[e] = expf(part[e] - mx); den += p[e]; }
    float inv = 1.f / den;
#pragma unroll
    for (int e = 0; e < NTOT; e++) p[e] *= inv;
    float s0 = -1e30f, s1 = -1e30f; int i0 = 0, i1 = 0;
#pragma unroll
    for (int e = 0; e < NTOT; e++) {
      float v = p[e] + bias[e];
      if (v > s0) { s1 = s0; i1 = i0; s0 = v; i0 = e; }
      else if (v > s1) { s1 = v; i1 = e; }
    }
    float zs = 0.f;
    int idx[2] = { i0, i1 };
#pragma unroll
    for (int k = 0; k < 2; k++) {
      int e = idx[k];
      float w = p[e];
      if (e >= NEXP) { zs += w; tk_e[2 * t + k] = -1; tk_w[2 * t + k] = 0.f; }
      else { tk_e[2 * t + k] = e; tk_w[2 * t + k] = w; atomicAdd(&lc[e], 1); }
    }
    zscale[t] = zs;
  }
  __syncthreads();
  if (tid < NEXP && lc[tid]) atomicAdd(&counts[tid], lc[tid]);
}

// ---------------- scan ----------------
__global__ void scan_kernel(const int* __restrict__ counts, int* __restrict__ cursor,
                            int* __restrict__ tile_e, int* __restrict__ tile_p0,
                            int* __restrict__ n_mtiles,
                            int* __restrict__ sel_tok, float* __restrict__ sel_w) {
  __shared__ int s_off[NEXP], s_cnt[NEXP];
  if (threadIdx.x == 0) {
    int run = 0, nt = 0;
    for (int e = 0; e < NEXP; e++) {
      s_off[e] = run; s_cnt[e] = counts[e];
      cursor[e] = run;
      int ntile = (s_cnt[e] + 127) / 128;
      for (int i = 0; i < ntile; i++) { tile_e[nt] = e; tile_p0[nt] = run + i * 128; nt++; }
      run += ntile * 128;
    }
    *n_mtiles = nt;
  }
  __syncthreads();
  for (int i = threadIdx.x; i < NEXP * 128; i += blockDim.x) {
    int e = i >> 7, idx = i & 127;
    int c = s_cnt[e];
    int padded = ((c + 127) / 128) * 128;
    int pos = c + idx;
    if (pos < padded) { sel_tok[s_off[e] + pos] = 0; sel_w[s_off[e] + pos] = 0.f; }
  }
}

// ---------------- assign ----------------
__global__ void assign_kernel(const int* __restrict__ tk_e, const float* __restrict__ tk_w,
                              int* __restrict__ cursor, int* __restrict__ sel_tok,
                              float* __restrict__ sel_w, int* __restrict__ pos) {
  __shared__ int lc[NEXP], lbase[NEXP];
  int tid = threadIdx.x;
  if (tid < NEXP) lc[tid] = 0;
  __syncthreads();
  int t = blockIdx.x * blockDim.x + tid;
  int e0 = tk_e[2 * t], e1 = tk_e[2 * t + 1];
  int r0 = (e0 >= 0) ? atomicAdd(&lc[e0], 1) : -1;
  int r1 = (e1 >= 0) ? atomicAdd(&lc[e1], 1) : -1;
  __syncthreads();
  if (tid < NEXP) lbase[tid] = lc[tid] ? atomicAdd(&cursor[tid], lc[tid]) : 0;
  __syncthreads();
  int p0 = -1, p1 = -1;
  if (e0 >= 0) { p0 = lbase[e0] + r0; sel_tok[p0] = t; sel_w[p0] = 2.5f * tk_w[2 * t]; }
  if (e1 >= 0) { p1 = lbase[e1] + r1; sel_tok[p1] = t; sel_w[p1] = 2.5f * tk_w[2 * t + 1]; }
  pos[2 * t] = p0;
  pos[2 * t + 1] = p1;
}

// ---------------- gather: xg[p0]=xg[p1]=bf16(x) ----------------
__global__ void gather_kernel(const float* __restrict__ x, const int* __restrict__ pos,
                              bf16_t* __restrict__ xg) {
  size_t gid = (size_t)blockIdx.x * blockDim.x + threadIdx.x;  // T * H/8
  size_t t = gid >> 7;
  int j = (int)(gid & 127) * 8;
  int p0 = pos[2 * t], p1 = pos[2 * t + 1];
  if (p0 < 0 && p1 < 0) return;
  float4 a = *(const float4*)&x[t * HDIM + j];
  float4 b = *(const float4*)&x[t * HDIM + j + 4];
  bf16x8 o = cvt8(a, b);
  if (p0 >= 0) *(bf16x8*)&xg[(size_t)p0 * HDIM + j] = o;
  if (p1 >= 0) *(bf16x8*)&xg[(size_t)p1 * HDIM + j] = o;
}

// ================= GEMM kernels =================
// BK=64: LDS rows of 128 B; chunk c (16 B) of row r stored at chunk c ^ (r&7).
// gll16 per call stages 8 rows x 8 chunks (dest contiguous 1 KB per wave);
// fragment ds_read_b128: quad q, k-half h reads stored chunk (h*4+q)^(r&7)
// -> 16 lanes spread over 8 chunk groups x 2 = 2-way bank aliasing = free.

// B-tile row r -> w13 col (gate/up interleaved, pairs land in same lane)
__device__ __forceinline__ int colmap1(int r, int g0) {
  return g0 + ((r >> 6) & 1) * 32 + (((r >> 4) & 1) * 16) + (r & 15) + (((r >> 5) & 1) ? IDIM : 0);
}

// ---------------- fused GEMM1+SiLU: 128 x (64 gate + 64 up) ----------------
__global__ __launch_bounds__(256) void gemm1_kernel(
    const bf16_t* __restrict__ xg, const bf16_t* __restrict__ w13b,
    const int* __restrict__ tile_e, const int* __restrict__ tile_p0,
    const int* __restrict__ n_mtiles, bf16_t* __restrict__ actb) {
  const int yb = blockIdx.x & 7;          // XCD-pinned weight slice
  const int ti = blockIdx.x >> 3;
  if (ti >= *n_mtiles) return;
  const int e = tile_e[ti];
  const int p0 = tile_p0[ti];
  const int g0 = yb * 64;

  __shared__ alignas(16) bf16_t As[128 * BK];
  __shared__ alignas(16) bf16_t Bs[128 * BK];
  const int tid = threadIdx.x;
  const int w = tid >> 6, l = tid & 63;
  const int wr = w >> 1, wc = w & 1;
  const int quad = l >> 4, c16 = l & 15;
  const int lrow = l >> 3, lch = l & 7;

  const bf16_t* w13e = w13b + (size_t)e * (2 * IDIM) * HDIM;
  const bf16_t* Asrc[4];
  const bf16_t* Bsrc[4];
  bf16_t* Adst[4];
  bf16_t* Bdst[4];
#pragma unroll
  for (int c = 0; c < 4; c++) {
    int r = w * 32 + c * 8 + lrow;
    int sch = (lch ^ (r & 7)) * 8;
    Asrc[c] = xg + (size_t)(p0 + r) * HDIM + sch;
    Bsrc[c] = w13e + (size_t)colmap1(r, g0) * HDIM + sch;
    Adst[c] = &As[(w * 32 + c * 8) * BK];
    Bdst[c] = &Bs[(w * 32 + c * 8) * BK];
  }

  int aoff[2][4], boff[2][4];
#pragma unroll
  for (int h = 0; h < 2; h++) {
#pragma unroll
    for (int mt = 0; mt < 4; mt++) {
      int r = wr * 64 + mt * 16 + c16;
      aoff[h][mt] = r * BK + (((h * 4 + quad) ^ (r & 7)) * 8);
    }
#pragma unroll
    for (int nt = 0; nt < 4; nt++) {
      int r = wc * 64 + nt * 16 + c16;
      boff[h][nt] = r * BK + (((h * 4 + quad) ^ (r & 7)) * 8);
    }
  }

  f32x4 acc[4][4];
#pragma unroll
  for (int i = 0; i < 4; i++)
#pragma unroll
    for (int j = 0; j < 4; j++) acc[i][j] = (f32x4){0.f, 0.f, 0.f, 0.f};

  for (int k0 = 0; k0 < HDIM; k0 += BK) {
#pragma unroll
    for (int c = 0; c < 4; c++) {
      gll16(Asrc[c] + k0, Adst[c]);
      gll16(Bsrc[c] + k0, Bdst[c]);
    }
    __syncthreads();
#pragma unroll
    for (int h = 0; h < 2; h++) {
      bf16x8 af[4], bfv[4];
#pragma unroll
      for (int mt = 0; mt < 4; mt++) af[mt] = *(const bf16x8*)&As[aoff[h][mt]];
#pragma unroll
      for (int nt = 0; nt < 4; nt++) bfv[nt] = *(const bf16x8*)&Bs[boff[h][nt]];
#pragma unroll
      for (int mt = 0; mt < 4; mt++)
#pragma unroll
        for (int nt = 0; nt < 4; nt++)
          acc[mt][nt] = __builtin_amdgcn_mfma_f32_16x16x32_bf16(af[mt], bfv[nt], acc[mt][nt], 0, 0, 0);
    }
    __syncthreads();
  }

  // epilogue: act = silu(gate)*up; gate=acc[mt][nt], up=acc[mt][nt+2] (same lane)
#pragma unroll
  for (int mt = 0; mt < 4; mt++) {
    int rowb = p0 + wr * 64 + mt * 16 + quad * 4;
#pragma unroll
    for (int nt = 0; nt < 2; nt++) {
      int col = g0 + wc * 32 + nt * 16 + c16;
#pragma unroll
      for (int r = 0; r < 4; r++) {
        float g = acc[mt][nt][r];
        float u = acc[mt][nt + 2][r];
        actb[(size_t)(rowb + r) * IDIM + col] = (bf16_t)(g / (1.f + expf(-g)) * u);
      }
    }
  }
}

// ---------------- GEMM2: 128x128 -> eob = sel_w * (act @ w2^T) ----------------
__global__ __launch_bounds__(256) void gemm2_kernel(
    const bf16_t* __restrict__ actb, const bf16_t* __restrict__ w2b,
    const float* __restrict__ sel_w, const int* __restrict__ tile_e,
    const int* __restrict__ tile_p0, const int* __restrict__ n_mtiles,
    bf16_t* __restrict__ eob) {
  const int yb = blockIdx.x & 7;
  const int ti = blockIdx.x >> 3;
  if (ti >= *n_mtiles) return;
  const int e = tile_e[ti];
  const int p0 = tile_p0[ti];
  const int n0 = yb * 128;

  __shared__ alignas(16) bf16_t As[128 * BK];
  __shared__ alignas(16) bf16_t Bs[128 * BK];
  const int tid = threadIdx.x;
  const int w = tid >> 6, l = tid & 63;
  const int wr = w >> 1, wc = w & 1;
  const int quad = l >> 4, c16 = l & 15;
  const int lrow = l >> 3, lch = l & 7;

  const bf16_t* w2e = w2b + (size_t)e * HDIM * IDIM;
  const bf16_t* Asrc[4];
  const bf16_t* Bsrc[4];
  bf16_t* Adst[4];
  bf16_t* Bdst[4];
#pragma unroll
  for (int c = 0; c < 4; c++) {
    int r = w * 32 + c * 8 + lrow;
    int sch = (lch ^ (r & 7)) * 8;
    Asrc[c] = actb + (size_t)(p0 + r) * IDIM + sch;
    Bsrc[c] = w2e + (size_t)(n0 + r) * IDIM + sch;
    Adst[c] = &As[(w * 32 + c * 8) * BK];
    Bdst[c] = &Bs[(w * 32 + c * 8) * BK];
  }

  int aoff[2][4], boff[2][4];
#pragma unroll
  for (int h = 0; h < 2; h++) {
#pragma unroll
    for (int mt = 0; mt < 4; mt++) {
      int r = wr * 64 + mt * 16 + c16;
      aoff[h][mt] = r * BK + (((h * 4 + quad) ^ (r & 7)) * 8);
    }
#pragma unroll
    for (int nt = 0; nt < 4; nt++) {
      int r = wc * 64 + nt * 16 + c16;
      boff[h][nt] = r * BK + (((h * 4 + quad) ^ (r & 7)) * 8);
    }
  }

  f32x4 acc[4][4];
#pragma unroll
  for (int i = 0; i < 4; i++)
#pragma unroll
    for (int j = 0; j < 4; j++) acc[i][j] = (f32x4){0.f, 0.f, 0.f, 0.f};

  for (int k0 = 0; k0 < IDIM; k0 += BK) {
#pragma unroll
    for (int c = 0; c < 4; c++) {
      gll16(Asrc[c] + k0, Adst[c]);
      gll16(Bsrc[c] + k0, Bdst[c]);
    }
    __syncthreads();
#pragma unroll
    for (int h = 0; h < 2; h++) {
      bf16x8 af[4], bfv[4];
#pragma unroll
      for (int mt = 0; mt < 4; mt++) af[mt] = *(const bf16x8*)&As[aoff[h][mt]];
#pragma unroll
      for (int nt = 0; nt < 4; nt++) bfv[nt] = *(const bf16x8*)&Bs[boff[h][nt]];
#pragma unroll
      for (int mt = 0; mt < 4; mt++)
#pragma unroll
        for (int nt = 0; nt < 4; nt++)
          acc[mt][nt] = __builtin_amdgcn_mfma_f32_16x16x32_bf16(af[mt], bfv[nt], acc[mt][nt], 0, 0, 0);
    }
    __syncthreads();
  }

  // epilogue: eob = sel_w * acc (bf16); pad rows (sel_w==0) skipped
#pragma unroll
  for (int mt = 0; mt < 4; mt++) {
    int rowb = p0 + wr * 64 + mt * 16 + quad * 4;
#pragma unroll
    for (int r = 0; r < 4; r++) {
      int p = rowb + r;
      float cw = sel_w[p];
      if (cw == 0.f) continue;
      size_t obase = (size_t)p * HDIM;
#pragma unroll
      for (int nt = 0; nt < 4; nt++) {
        int col = n0 + wc * 64 + nt * 16 + c16;
        eob[obase + col] = (bf16_t)(cw * acc[mt][nt][r]);
      }
    }
  }
}

// ---------------- final combine: out = zs*x + eob[pos0] + eob[pos1] ----------------
__global__ void combine_kernel(const float* __restrict__ x, const float* __restrict__ zscale,
                               const int* __restrict__ pos, const bf16_t* __restrict__ eob,
                               float* __restrict__ out) {
  size_t gid = (size_t)blockIdx.x * blockDim.x + threadIdx.x;
  size_t t = gid >> 7;
  size_t j = (gid & 127) << 3;
  float zs = zscale[t];
  int p0 = pos[2 * t], p1 = pos[2 * t + 1];
  float4 a = *(const float4*)&x[t * HDIM + j];
  float4 b = *(const float4*)&x[t * HDIM + j + 4];
  float o[8] = { zs * a.x, zs * a.y, zs * a.z, zs * a.w,
                 zs * b.x, zs * b.y, zs * b.z, zs * b.w };
  if (p0 >= 0) {
    bf16x8 v = *(const bf16x8*)&eob[(size_t)p0 * HDIM + j];
#pragma unroll
    for (int k = 0; k < 8; k++) o[k] += (float)v[k];
  }
  if (p1 >= 0) {
    bf16x8 v = *(const bf16x8*)&eob[(size_t)p1 * HDIM + j];
#pragma unroll
    for (int k = 0; k < 8; k++) o[k] += (float)v[k];
  }
  *(float4*)&out[t * HDIM + j] = make_float4(o[0], o[1], o[2], o[3]);
  *(float4*)&out[t * HDIM + j + 4] = make_float4(o[4], o[5], o[6], o[7]);
}

extern "C" void kernel_launch(void* const* d_in, const int* in_sizes, int n_in,
                              void* d_out, int out_size, void* d_ws, size_t ws_size,
                              hipStream_t stream) {
  const float* x    = (const float*)d_in[0];
  const float* rw   = (const float*)d_in[1];
  const float* bias = (const float*)d_in[2];
  const float* w13  = (const float*)d_in[3];
  const float* w2   = (const float*)d_in[4];
  float* out = (float*)d_out;

  char* ws = (char*)d_ws;
  bf16_t* w13b = (bf16_t*)ws;  ws += (size_t)NEXP * 2 * IDIM * HDIM * 2;
  bf16_t* w2b  = (bf16_t*)ws;  ws += (size_t)NEXP * HDIM * IDIM * 2;
  bf16_t* xg   = (bf16_t*)ws;  ws += (size_t)MAXROWS * HDIM * 2;
  bf16_t* actb = (bf16_t*)ws;  ws += (size_t)MAXROWS * IDIM * 2;
  bf16_t* eob  = (bf16_t*)ws;  ws += (size_t)MAXROWS * HDIM * 2;
  int*   tk_e    = (int*)ws;   ws += (size_t)T_TOK * 2 * 4;
  float* tk_w    = (float*)ws; ws += (size_t)T_TOK * 2 * 4;
  float* zscale  = (float*)ws; ws += (size_t)T_TOK * 4;
  int*   pos     = (int*)ws;   ws += (size_t)T_TOK * 2 * 4;
  int*   sel_tok = (int*)ws;   ws += (size_t)MAXROWS * 4;
  float* sel_w   = (float*)ws; ws += (size_t)MAXROWS * 4;
  int*   counts  = (int*)ws;   ws += NEXP * 4;
  int*   cursor  = (int*)ws;   ws += NEXP * 4;
  int*   tile_e  = (int*)ws;   ws += MAX_MTILES * 4;
  int*   tile_p0 = (int*)ws;   ws += MAX_MTILES * 4;
  int*   n_mtiles = (int*)ws;  ws += 4;

  zero_counts_kernel<<<1, 64, 0, stream>>>(counts);
  cast_w_kernel<<<(N1G + N2G + 255) / 256, 256, 0, stream>>>(w13, w2, w13b, w2b);
  router_kernel<<<T_TOK / 4, 256, 0, stream>>>(x, rw, bias, tk_e, tk_w, zscale, counts);
  scan_kernel<<<1, 256, 0, stream>>>(counts, cursor, tile_e, tile_p0, n_mtiles, sel_tok, sel_w);
  assign_kernel<<<T_TOK / 256, 256, 0, stream>>>(tk_e, tk_w, cursor, sel_tok, sel_w, pos);
  gather_kernel<<<(size_t)T_TOK * (HDIM / 8) / 256, 256, 0, stream>>>(x, pos, xg);

  gemm1_kernel<<<MAX_MTILES * 8, 256, 0, stream>>>(
      xg, w13b, tile_e, tile_p0, n_mtiles, actb);
  gemm2_kernel<<<MAX_MTILES * 8, 256, 0, stream>>>(
      actb, w2b, sel_w, tile_e, tile_p0, n_mtiles, eob);

  combine_kernel<<<(size_t)T_TOK * HDIM / 8 / 256, 256, 0, stream>>>(
      x, zscale, pos, eob, out);
}

// Round 9
// 247.220 us; speedup vs baseline: 1.4302x; 1.0486x over previous
//
#include <hip/hip_runtime.h>
#include <hip/hip_bf16.h>
#include <math.h>

typedef __bf16 bf16_t;
typedef bf16_t bf16x8 __attribute__((ext_vector_type(8)));
typedef float f32x4 __attribute__((ext_vector_type(4)));

#define T_TOK 8192
#define HDIM  1024
#define IDIM  512
#define NEXP  8
#define NTOT  12
#define MAXROWS (2 * T_TOK + NEXP * 128)   // 17408
#define MAX_MTILES (MAXROWS / 128)         // 136

// ---------------- async global->LDS, 16B per lane ----------------
__device__ __forceinline__ void gll16(const bf16_t* g, bf16_t* l) {
  __builtin_amdgcn_global_load_lds((__attribute__((address_space(1))) void*)g,
                                   (__attribute__((address_space(3))) void*)l,
                                   16, 0, 0);
}

__device__ __forceinline__ bf16x8 cvt8(float4 f0, float4 f1) {
  bf16x8 t;
  t[0] = (bf16_t)f0.x; t[1] = (bf16_t)f0.y; t[2] = (bf16_t)f0.z; t[3] = (bf16_t)f0.w;
  t[4] = (bf16_t)f1.x; t[5] = (bf16_t)f1.y; t[6] = (bf16_t)f1.z; t[7] = (bf16_t)f1.w;
  return t;
}

// ---------------- fused weight cast (+ zero counts in block 0) ----------------
#define N1G (NEXP * 2 * IDIM * HDIM / 8)
#define N2G (NEXP * HDIM * IDIM / 8)
__global__ void cast_w_kernel(const float* __restrict__ w13, const float* __restrict__ w2,
                              bf16_t* __restrict__ w13b, bf16_t* __restrict__ w2b,
                              int* __restrict__ counts) {
  if (blockIdx.x == 0 && threadIdx.x < NEXP) counts[threadIdx.x] = 0;
  size_t gid = (size_t)blockIdx.x * blockDim.x + threadIdx.x;
  const float* src;
  bf16_t* dst;
  if (gid < N1G) { src = w13 + gid * 8; dst = w13b + gid * 8; }
  else { size_t g2 = gid - N1G; if (g2 >= N2G) return; src = w2 + g2 * 8; dst = w2b + g2 * 8; }
  float4 a = *(const float4*)src;
  float4 b = *(const float4*)(src + 4);
  *(bf16x8*)dst = cvt8(a, b);
}

// ---------------- router + count ----------------
__global__ void router_kernel(const float* __restrict__ x, const float* __restrict__ rw,
                              const float* __restrict__ bias,
                              int* __restrict__ tk_e, float* __restrict__ tk_w,
                              float* __restrict__ zscale, int* __restrict__ counts) {
  __shared__ int lc[NEXP];
  int tid = threadIdx.x;
  if (tid < NEXP) lc[tid] = 0;
  __syncthreads();
  int t = blockIdx.x * 4 + (tid >> 6);
  int l = tid & 63;
  const float4* xr = (const float4*)(x + (size_t)t * HDIM);
  float4 xv[4];
#pragma unroll
  for (int i = 0; i < 4; i++) xv[i] = xr[l + 64 * i];
  float part[NTOT];
#pragma unroll
  for (int e = 0; e < NTOT; e++) {
    const float4* wr = (const float4*)(rw + (size_t)e * HDIM);
    float s = 0.f;
#pragma unroll
    for (int i = 0; i < 4; i++) {
      float4 w = wr[l + 64 * i];
      s += xv[i].x * w.x + xv[i].y * w.y + xv[i].z * w.z + xv[i].w * w.w;
    }
    part[e] = s;
  }
#pragma unroll
  for (int off = 32; off > 0; off >>= 1)
#pragma unroll
    for (int e = 0; e < NTOT; e++) part[e] += __shfl_down(part[e], off);

  if (l == 0) {
    float mx = part[0];
#pragma unroll
    for (int e = 1; e < NTOT; e++) mx = fmaxf(mx, part[e]);
    float p[NTOT], den = 0.f;
#pragma unroll
    for (int e = 0; e < NTOT; e++) { p[e] = expf(part[e] - mx); den += p[e]; }
    float inv = 1.f / den;
#pragma unroll
    for (int e = 0; e < NTOT; e++) p[e] *= inv;
    float s0 = -1e30f, s1 = -1e30f; int i0 = 0, i1 = 0;
#pragma unroll
    for (int e = 0; e < NTOT; e++) {
      float v = p[e] + bias[e];
      if (v > s0) { s1 = s0; i1 = i0; s0 = v; i0 = e; }
      else if (v > s1) { s1 = v; i1 = e; }
    }
    float zs = 0.f;
    int idx[2] = { i0, i1 };
#pragma unroll
    for (int k = 0; k < 2; k++) {
      int e = idx[k];
      float w = p[e];
      if (e >= NEXP) { zs += w; tk_e[2 * t + k] = -1; tk_w[2 * t + k] = 0.f; }
      else { tk_e[2 * t + k] = e; tk_w[2 * t + k] = w; atomicAdd(&lc[e], 1); }
    }
    zscale[t] = zs;
  }
  __syncthreads();
  if (tid < NEXP && lc[tid]) atomicAdd(&counts[tid], lc[tid]);
}

// ---------------- scan: tile list + cursor + zero pad sel entries ----------------
__global__ void scan_kernel(const int* __restrict__ counts, int* __restrict__ cursor,
                            int* __restrict__ tile_e, int* __restrict__ tile_p0,
                            int* __restrict__ n_mtiles,
                            int* __restrict__ sel_tok, float* __restrict__ sel_w) {
  __shared__ int s_off[NEXP], s_cnt[NEXP];
  if (threadIdx.x == 0) {
    int run = 0, nt = 0;
    for (int e = 0; e < NEXP; e++) {
      s_off[e] = run; s_cnt[e] = counts[e];
      cursor[e] = run;
      int ntile = (s_cnt[e] + 127) / 128;
      for (int i = 0; i < ntile; i++) { tile_e[nt] = e; tile_p0[nt] = run + i * 128; nt++; }
      run += ntile * 128;
    }
    *n_mtiles = nt;
  }
  __syncthreads();
  for (int i = threadIdx.x; i < NEXP * 128; i += blockDim.x) {
    int e = i >> 7, idx = i & 127;
    int c = s_cnt[e];
    int padded = ((c + 127) / 128) * 128;
    int pos = c + idx;
    if (pos < padded) { sel_tok[s_off[e] + pos] = 0; sel_w[s_off[e] + pos] = 0.f; }
  }
}

// ---------------- assign ----------------
__global__ void assign_kernel(const int* __restrict__ tk_e, const float* __restrict__ tk_w,
                              int* __restrict__ cursor, int* __restrict__ sel_tok,
                              float* __restrict__ sel_w, int* __restrict__ pos) {
  __shared__ int lc[NEXP], lbase[NEXP];
  int tid = threadIdx.x;
  if (tid < NEXP) lc[tid] = 0;
  __syncthreads();
  int t = blockIdx.x * blockDim.x + tid;
  int e0 = tk_e[2 * t], e1 = tk_e[2 * t + 1];
  int r0 = (e0 >= 0) ? atomicAdd(&lc[e0], 1) : -1;
  int r1 = (e1 >= 0) ? atomicAdd(&lc[e1], 1) : -1;
  __syncthreads();
  if (tid < NEXP) lbase[tid] = lc[tid] ? atomicAdd(&cursor[tid], lc[tid]) : 0;
  __syncthreads();
  int p0 = -1, p1 = -1;
  if (e0 >= 0) { p0 = lbase[e0] + r0; sel_tok[p0] = t; sel_w[p0] = 2.5f * tk_w[2 * t]; }
  if (e1 >= 0) { p1 = lbase[e1] + r1; sel_tok[p1] = t; sel_w[p1] = 2.5f * tk_w[2 * t + 1]; }
  pos[2 * t] = p0;
  pos[2 * t + 1] = p1;
}

// ---------------- gather: xg[p0]=xg[p1]=bf16(x) ----------------
__global__ void gather_kernel(const float* __restrict__ x, const int* __restrict__ pos,
                              bf16_t* __restrict__ xg) {
  size_t gid = (size_t)blockIdx.x * blockDim.x + threadIdx.x;  // T * H/8
  size_t t = gid >> 7;
  int j = (int)(gid & 127) * 8;
  int p0 = pos[2 * t], p1 = pos[2 * t + 1];
  if (p0 < 0 && p1 < 0) return;
  float4 a = *(const float4*)&x[t * HDIM + j];
  float4 b = *(const float4*)&x[t * HDIM + j + 4];
  bf16x8 o = cvt8(a, b);
  if (p0 >= 0) *(bf16x8*)&xg[(size_t)p0 * HDIM + j] = o;
  if (p1 >= 0) *(bf16x8*)&xg[(size_t)p1 * HDIM + j] = o;
}

// ================= GEMM kernels (round-7 proven structure) =================
// BK=32, row-major 64-B LDS rows; chunk XOR-swizzled at the SOURCE side:
// LDS(row, chunk j) = src(row, j ^ ((row>>1)&3)); fragment read offset
// r*32 + ((quad ^ ((r>>1)&3))*8) -> measured 0 bank conflicts (r5/r7).

// ---------------- fused GEMM1+SiLU: 128 x 64(gate)+64(up) interleaved ----------------
__global__ __launch_bounds__(256) void gemm1_kernel(
    const bf16_t* __restrict__ xg, const bf16_t* __restrict__ w13b,
    const int* __restrict__ tile_e, const int* __restrict__ tile_p0,
    const int* __restrict__ n_mtiles, bf16_t* __restrict__ actb) {
  const int yb = blockIdx.x & 7;          // XCD-pinned weight slice
  const int ti = blockIdx.x >> 3;
  if (ti >= *n_mtiles) return;
  const int e = tile_e[ti];
  const int p0 = tile_p0[ti];
  const int g0 = yb * 64;

  __shared__ alignas(16) bf16_t As[128 * 32];
  __shared__ alignas(16) bf16_t Bs[128 * 32];
  const int tid = threadIdx.x;
  const int w = tid >> 6, l = tid & 63;
  const int wr = w >> 1, wc = w & 1;
  const int quad = l >> 4, c16 = l & 15;

  const int sr = w * 32 + (l >> 2);
  const int sr1 = sr + 16;
  const int sc0 = ((l & 3) ^ ((sr >> 1) & 3)) * 8;
  const int sc1 = ((l & 3) ^ ((sr1 >> 1) & 3)) * 8;
  const bf16_t* Ag0 = xg + (size_t)(p0 + sr) * HDIM + sc0;
  const bf16_t* Ag1 = xg + (size_t)(p0 + sr1) * HDIM + sc1;
  int col0 = g0 + (sr >> 6) * 32 + (((sr >> 4) & 1) * 16) + (sr & 15) + (((sr >> 5) & 1) ? IDIM : 0);
  int col1 = g0 + (sr1 >> 6) * 32 + (((sr1 >> 4) & 1) * 16) + (sr1 & 15) + (((sr1 >> 5) & 1) ? IDIM : 0);
  const bf16_t* w13e = w13b + (size_t)e * (2 * IDIM) * HDIM;
  const bf16_t* Bg0 = w13e + (size_t)col0 * HDIM + sc0;
  const bf16_t* Bg1 = w13e + (size_t)col1 * HDIM + sc1;
  bf16_t* Al0 = &As[(w * 32) * 32];
  bf16_t* Bl0 = &Bs[(w * 32) * 32];

  int aoff[4], boff[4];
#pragma unroll
  for (int mt = 0; mt < 4; mt++) {
    int r = wr * 64 + mt * 16 + c16;
    aoff[mt] = r * 32 + ((quad ^ ((r >> 1) & 3)) * 8);
  }
#pragma unroll
  for (int nt = 0; nt < 4; nt++) {
    int r = wc * 64 + nt * 16 + c16;
    boff[nt] = r * 32 + ((quad ^ ((r >> 1) & 3)) * 8);
  }

  f32x4 acc[4][4];
#pragma unroll
  for (int i = 0; i < 4; i++)
#pragma unroll
    for (int j = 0; j < 4; j++) acc[i][j] = (f32x4){0.f, 0.f, 0.f, 0.f};

  for (int k0 = 0; k0 < HDIM; k0 += 32) {
    gll16(Ag0 + k0, Al0);
    gll16(Ag1 + k0, Al0 + 16 * 32);
    gll16(Bg0 + k0, Bl0);
    gll16(Bg1 + k0, Bl0 + 16 * 32);
    __syncthreads();
    bf16x8 af[4], bfv[4];
#pragma unroll
    for (int mt = 0; mt < 4; mt++) af[mt] = *(const bf16x8*)&As[aoff[mt]];
#pragma unroll
    for (int nt = 0; nt < 4; nt++) bfv[nt] = *(const bf16x8*)&Bs[boff[nt]];
#pragma unroll
    for (int mt = 0; mt < 4; mt++)
#pragma unroll
      for (int nt = 0; nt < 4; nt++)
        acc[mt][nt] = __builtin_amdgcn_mfma_f32_16x16x32_bf16(af[mt], bfv[nt], acc[mt][nt], 0, 0, 0);
    __syncthreads();
  }

  // epilogue: act = silu(gate)*up; gate=acc[mt][nt], up=acc[mt][nt+2] (same lane)
#pragma unroll
  for (int mt = 0; mt < 4; mt++) {
    int rowb = p0 + wr * 64 + mt * 16 + quad * 4;
#pragma unroll
    for (int nt = 0; nt < 2; nt++) {
      int col = g0 + wc * 32 + nt * 16 + c16;
#pragma unroll
      for (int r = 0; r < 4; r++) {
        float g = acc[mt][nt][r];
        float u = acc[mt][nt + 2][r];
        actb[(size_t)(rowb + r) * IDIM + col] = (bf16_t)(g / (1.f + expf(-g)) * u);
      }
    }
  }
}

// ---------------- GEMM2: 128x128 -> eob = sel_w * (act @ w2^T) ----------------
__global__ __launch_bounds__(256) void gemm2_kernel(
    const bf16_t* __restrict__ actb, const bf16_t* __restrict__ w2b,
    const float* __restrict__ sel_w, const int* __restrict__ tile_e,
    const int* __restrict__ tile_p0, const int* __restrict__ n_mtiles,
    bf16_t* __restrict__ eob) {
  const int yb = blockIdx.x & 7;
  const int ti = blockIdx.x >> 3;
  if (ti >= *n_mtiles) return;
  const int e = tile_e[ti];
  const int p0 = tile_p0[ti];
  const int n0 = yb * 128;

  __shared__ alignas(16) bf16_t As[128 * 32];
  __shared__ alignas(16) bf16_t Bs[128 * 32];
  const int tid = threadIdx.x;
  const int w = tid >> 6, l = tid & 63;
  const int wr = w >> 1, wc = w & 1;
  const int quad = l >> 4, c16 = l & 15;

  const int sr = w * 32 + (l >> 2);
  const int sr1 = sr + 16;
  const int sc0 = ((l & 3) ^ ((sr >> 1) & 3)) * 8;
  const int sc1 = ((l & 3) ^ ((sr1 >> 1) & 3)) * 8;
  const bf16_t* Ag0 = actb + (size_t)(p0 + sr) * IDIM + sc0;
  const bf16_t* Ag1 = actb + (size_t)(p0 + sr1) * IDIM + sc1;
  const bf16_t* w2e = w2b + (size_t)e * HDIM * IDIM;
  const bf16_t* Bg0 = w2e + (size_t)(n0 + sr) * IDIM + sc0;
  const bf16_t* Bg1 = w2e + (size_t)(n0 + sr1) * IDIM + sc1;
  bf16_t* Al0 = &As[(w * 32) * 32];
  bf16_t* Bl0 = &Bs[(w * 32) * 32];

  int aoff[4], boff[4];
#pragma unroll
  for (int mt = 0; mt < 4; mt++) {
    int r = wr * 64 + mt * 16 + c16;
    aoff[mt] = r * 32 + ((quad ^ ((r >> 1) & 3)) * 8);
  }
#pragma unroll
  for (int nt = 0; nt < 4; nt++) {
    int r = wc * 64 + nt * 16 + c16;
    boff[nt] = r * 32 + ((quad ^ ((r >> 1) & 3)) * 8);
  }

  f32x4 acc[4][4];
#pragma unroll
  for (int i = 0; i < 4; i++)
#pragma unroll
    for (int j = 0; j < 4; j++) acc[i][j] = (f32x4){0.f, 0.f, 0.f, 0.f};

  for (int k0 = 0; k0 < IDIM; k0 += 32) {
    gll16(Ag0 + k0, Al0);
    gll16(Ag1 + k0, Al0 + 16 * 32);
    gll16(Bg0 + k0, Bl0);
    gll16(Bg1 + k0, Bl0 + 16 * 32);
    __syncthreads();
    bf16x8 af[4], bfv[4];
#pragma unroll
    for (int mt = 0; mt < 4; mt++) af[mt] = *(const bf16x8*)&As[aoff[mt]];
#pragma unroll
    for (int nt = 0; nt < 4; nt++) bfv[nt] = *(const bf16x8*)&Bs[boff[nt]];
#pragma unroll
    for (int mt = 0; mt < 4; mt++)
#pragma unroll
      for (int nt = 0; nt < 4; nt++)
        acc[mt][nt] = __builtin_amdgcn_mfma_f32_16x16x32_bf16(af[mt], bfv[nt], acc[mt][nt], 0, 0, 0);
    __syncthreads();
  }

  // epilogue: eob = sel_w * acc (bf16); pad rows (sel_w==0) skipped
#pragma unroll
  for (int mt = 0; mt < 4; mt++) {
    int rowb = p0 + wr * 64 + mt * 16 + quad * 4;
#pragma unroll
    for (int r = 0; r < 4; r++) {
      int p = rowb + r;
      float cw = sel_w[p];
      if (cw == 0.f) continue;
      size_t obase = (size_t)p * HDIM;
#pragma unroll
      for (int nt = 0; nt < 4; nt++) {
        int col = n0 + wc * 64 + nt * 16 + c16;
        eob[obase + col] = (bf16_t)(cw * acc[mt][nt][r]);
      }
    }
  }
}

// ---------------- final combine: out = zs*x + eob[pos0] + eob[pos1] ----------------
__global__ void combine_kernel(const float* __restrict__ x, const float* __restrict__ zscale,
                               const int* __restrict__ pos, const bf16_t* __restrict__ eob,
                               float* __restrict__ out) {
  size_t gid = (size_t)blockIdx.x * blockDim.x + threadIdx.x;
  size_t t = gid >> 7;
  size_t j = (gid & 127) << 3;
  float zs = zscale[t];
  int p0 = pos[2 * t], p1 = pos[2 * t + 1];
  float4 a = *(const float4*)&x[t * HDIM + j];
  float4 b = *(const float4*)&x[t * HDIM + j + 4];
  float o[8] = { zs * a.x, zs * a.y, zs * a.z, zs * a.w,
                 zs * b.x, zs * b.y, zs * b.z, zs * b.w };
  if (p0 >= 0) {
    bf16x8 v = *(const bf16x8*)&eob[(size_t)p0 * HDIM + j];
#pragma unroll
    for (int k = 0; k < 8; k++) o[k] += (float)v[k];
  }
  if (p1 >= 0) {
    bf16x8 v = *(const bf16x8*)&eob[(size_t)p1 * HDIM + j];
#pragma unroll
    for (int k = 0; k < 8; k++) o[k] += (float)v[k];
  }
  *(float4*)&out[t * HDIM + j] = make_float4(o[0], o[1], o[2], o[3]);
  *(float4*)&out[t * HDIM + j + 4] = make_float4(o[4], o[5], o[6], o[7]);
}

extern "C" void kernel_launch(void* const* d_in, const int* in_sizes, int n_in,
                              void* d_out, int out_size, void* d_ws, size_t ws_size,
                              hipStream_t stream) {
  const float* x    = (const float*)d_in[0];
  const float* rw   = (const float*)d_in[1];
  const float* bias = (const float*)d_in[2];
  const float* w13  = (const float*)d_in[3];
  const float* w2   = (const float*)d_in[4];
  float* out = (float*)d_out;

  char* ws = (char*)d_ws;
  bf16_t* w13b = (bf16_t*)ws;  ws += (size_t)NEXP * 2 * IDIM * HDIM * 2;
  bf16_t* w2b  = (bf16_t*)ws;  ws += (size_t)NEXP * HDIM * IDIM * 2;
  bf16_t* xg   = (bf16_t*)ws;  ws += (size_t)MAXROWS * HDIM * 2;
  bf16_t* actb = (bf16_t*)ws;  ws += (size_t)MAXROWS * IDIM * 2;
  bf16_t* eob  = (bf16_t*)ws;  ws += (size_t)MAXROWS * HDIM * 2;
  int*   tk_e    = (int*)ws;   ws += (size_t)T_TOK * 2 * 4;
  float* tk_w    = (float*)ws; ws += (size_t)T_TOK * 2 * 4;
  float* zscale  = (float*)ws; ws += (size_t)T_TOK * 4;
  int*   pos     = (int*)ws;   ws += (size_t)T_TOK * 2 * 4;
  int*   sel_tok = (int*)ws;   ws += (size_t)MAXROWS * 4;
  float* sel_w   = (float*)ws; ws += (size_t)MAXROWS * 4;
  int*   counts  = (int*)ws;   ws += NEXP * 4;
  int*   cursor  = (int*)ws;   ws += NEXP * 4;
  int*   tile_e  = (int*)ws;   ws += MAX_MTILES * 4;
  int*   tile_p0 = (int*)ws;   ws += MAX_MTILES * 4;
  int*   n_mtiles = (int*)ws;  ws += 4;

  cast_w_kernel<<<(N1G + N2G + 255) / 256, 256, 0, stream>>>(w13, w2, w13b, w2b, counts);
  router_kernel<<<T_TOK / 4, 256, 0, stream>>>(x, rw, bias, tk_e, tk_w, zscale, counts);
  scan_kernel<<<1, 256, 0, stream>>>(counts, cursor, tile_e, tile_p0, n_mtiles, sel_tok, sel_w);
  assign_kernel<<<T_TOK / 256, 256, 0, stream>>>(tk_e, tk_w, cursor, sel_tok, sel_w, pos);
  gather_kernel<<<(size_t)T_TOK * (HDIM / 8) / 256, 256, 0, stream>>>(x, pos, xg);

  gemm1_kernel<<<MAX_MTILES * 8, 256, 0, stream>>>(
      xg, w13b, tile_e, tile_p0, n_mtiles, actb);
  gemm2_kernel<<<MAX_MTILES * 8, 256, 0, stream>>>(
      actb, w2b, sel_w, tile_e, tile_p0, n_mtiles, eob);

  combine_kernel<<<(size_t)T_TOK * HDIM / 8 / 256, 256, 0, stream>>>(
      x, zscale, pos, eob, out);
}